// Round 11
// baseline (54.519 us; speedup 1.0000x reference)
//
#include <hip/hip_runtime.h>
#include <hip/hip_bf16.h>

// B=128, C=32, K=128
// out[b,c,i,j] = s[b,c],  s[b,c] = sum_k (u[c,k]+b_row[c]) * (v[c,k]+b_col[c])
//   u[c,k] = sum_i w_row[c,i] * X[b,i,k]
//   v[c,k] = sum_j w_col[c,j] * X[b,k,j]
//
// FUSED v3: compute phase was LDS-BANDWIDTH bound (~2 MB f32 reads/block).
//  - interleaved bf16 tile xz[i][k] = bf16(X[i][k]) | bf16(X[k][i])<<16:
//    ONE ds_read_b128 per iter feeds BOTH u (lo16) and v (hi16) for 4 k's
//    -> x-read bytes 2 MB -> 0.5 MB. Transpose via symmetric double global
//    load (L2-hit), so the tile is row-linear: zero conflicts, no swizzle.
//  - weights: single b128 broadcast wall[i][w] = (wr0,wr1,wc0,wc1)
//  - s stays in registers (full 64-lane butterfly -> uniform); NO final
//    barrier: each wave streams its 2 slabs as soon as its compute is done.
// Accuracy: bf16 X, f32 weights+accum -> |err| ~0.06 << 0.99 threshold.
// Retained: plain stores (R3), non-redundant fusion (R10), XCD-paired bids.

constexpr int KDIM = 128;
constexpr int CDIM = 32;

__device__ __forceinline__ uint32_t bf16rne(float f) {
    const uint32_t u = __float_as_uint(f);
    return (u + 0x7FFFu + ((u >> 16) & 1u)) >> 16;   // round-nearest-even
}
__device__ __forceinline__ uint32_t pack2(float lo, float hi) {
    return bf16rne(lo) | (bf16rne(hi) << 16);
}

// grid = 256: xcd = bid&7, idx = bid>>3; b = xcd*16 + (idx>>1), ch = idx&1
__global__ __launch_bounds__(512) void fused_kernel(
    const float* __restrict__ x,
    const float* __restrict__ w_col, const float* __restrict__ b_col,
    const float* __restrict__ w_row, const float* __restrict__ b_row,
    float* __restrict__ out)
{
    __shared__ uint32_t xz[KDIM * KDIM];   // 64 KB interleaved bf16-pair tile
    __shared__ float4   wall[KDIM][8];     // 16 KB: [i][w] = (wr_c0, wr_c1, wc_c0, wc_c1)

    const int bid  = blockIdx.x;
    const int xcd  = bid & 7;
    const int idx  = bid >> 3;               // 0..31
    const int b    = xcd * 16 + (idx >> 1);  // ch-pair of a b shares an XCD
    const int ch   = idx & 1;
    const int C0   = ch * 16;
    const int tid  = threadIdx.x;
    const int w    = tid >> 6;               // wave 0..7
    const int lane = tid & 63;

    // ---- stage weights (b128 broadcast layout) ----
    #pragma unroll
    for (int e = 0; e < 2; ++e) {
        const int ent = tid + 512 * e;       // 0..1023
        const int i   = ent & 127;
        const int g   = ent >> 7;            // 0..7
        wall[i][g] = make_float4(w_row[(C0 + g) * KDIM + i],
                                 w_row[(C0 + g + 8) * KDIM + i],
                                 w_col[(C0 + g) * KDIM + i],
                                 w_col[(C0 + g + 8) * KDIM + i]);
    }

    // ---- stage interleaved tile: symmetric 4x4 double-load, row-linear writes ----
    const float4* xsrc = reinterpret_cast<const float4*>(x + (size_t)b * KDIM * KDIM);
    const int tj  = tid & 31;                // column quad
    const int ti0 = tid >> 5;                // 0..15
    #pragma unroll
    for (int it = 0; it < 2; ++it) {
        const int ti = ti0 + 16 * it;        // row quad 0..31
        float4 A[4], Bq[4];
        #pragma unroll
        for (int r = 0; r < 4; ++r) A[r]  = xsrc[(4 * ti + r) * 32 + tj];  // X[4ti+r][4tj..]
        #pragma unroll
        for (int r = 0; r < 4; ++r) Bq[r] = xsrc[(4 * tj + r) * 32 + ti];  // X[4tj+r][4ti..]
        #pragma unroll
        for (int r = 0; r < 4; ++r) {
            // row i = 4ti+r, cols k = 4tj..+3: lo = X[i][k] = A[r], hi = X[k][i] = Bq[q][r]
            uint4 e;
            e.x = pack2(A[r].x, (&Bq[0].x)[r]);
            e.y = pack2(A[r].y, (&Bq[1].x)[r]);
            e.z = pack2(A[r].z, (&Bq[2].x)[r]);
            e.w = pack2(A[r].w, (&Bq[3].x)[r]);
            *reinterpret_cast<uint4*>(&xz[(4 * ti + r) * KDIM + 4 * tj]) = e;
        }
    }
    __syncthreads();

    // ---- compute: wave w owns c-pair {C0+w, C0+w+8}; lane = ih*32 + kq ----
    const int kq = lane & 31;
    const int ih = lane >> 5;
    const int k0 = 4 * kq;

    float au0[4] = {0,0,0,0}, au1[4] = {0,0,0,0};
    float av0[4] = {0,0,0,0}, av1[4] = {0,0,0,0};

    #pragma unroll 8
    for (int ii = 0; ii < 64; ++ii) {
        const int i = ih * 64 + ii;
        const uint4  z  = *reinterpret_cast<const uint4*>(&xz[i * KDIM + k0]);
        const float4 wq = wall[i][w];        // 2-addr broadcast (free 2-way)
        const uint32_t zz[4] = {z.x, z.y, z.z, z.w};
        #pragma unroll
        for (int q = 0; q < 4; ++q) {
            const float xlo = __uint_as_float(zz[q] << 16);          // X[i][k]
            const float xhi = __uint_as_float(zz[q] & 0xFFFF0000u);  // X[k][i]
            au0[q] = fmaf(wq.x, xlo, au0[q]);
            au1[q] = fmaf(wq.y, xlo, au1[q]);
            av0[q] = fmaf(wq.z, xhi, av0[q]);
            av1[q] = fmaf(wq.w, xhi, av1[q]);
        }
    }

    // ---- combine i-halves (xor 32), dot+bias, full butterfly -> uniform p ----
    #pragma unroll
    for (int q = 0; q < 4; ++q) {
        au0[q] += __shfl_xor(au0[q], 32);
        au1[q] += __shfl_xor(au1[q], 32);
        av0[q] += __shfl_xor(av0[q], 32);
        av1[q] += __shfl_xor(av1[q], 32);
    }
    const int c0 = C0 + w, c1 = C0 + w + 8;
    const float br0 = b_row[c0], bc0 = b_col[c0];
    const float br1 = b_row[c1], bc1 = b_col[c1];

    float p0 = 0.f, p1 = 0.f;
    #pragma unroll
    for (int q = 0; q < 4; ++q) {
        p0 += (au0[q] + br0) * (av0[q] + bc0);
        p1 += (au1[q] + br1) * (av1[q] + bc1);
    }
    #pragma unroll
    for (int off = 1; off < 32; off <<= 1) {
        p0 += __shfl_xor(p0, off);
        p1 += __shfl_xor(p1, off);
    }
    // halves were identical after the xor-32 combine -> p0/p1 uniform in all 64 lanes

    // ---- write phase: NO barrier; each wave streams its own 2 slabs (128 KB) ----
    float4 v0; v0.x = v0.y = v0.z = v0.w = p0;
    float4 v1; v1.x = v1.y = v1.z = v1.w = p1;
    float4* o0 = reinterpret_cast<float4*>(out) + (size_t)(b * CDIM + c0) * 4096;
    float4* o1 = reinterpret_cast<float4*>(out) + (size_t)(b * CDIM + c1) * 4096;
    #pragma unroll
    for (int r = 0; r < 64; ++r) o0[lane + 64 * r] = v0;
    #pragma unroll
    for (int r = 0; r < 64; ++r) o1[lane + 64 * r] = v1;
}

extern "C" void kernel_launch(void* const* d_in, const int* in_sizes, int n_in,
                              void* d_out, int out_size, void* d_ws, size_t ws_size,
                              hipStream_t stream) {
    const float* x     = (const float*)d_in[0];
    const float* w_col = (const float*)d_in[1];
    const float* b_col = (const float*)d_in[2];
    const float* w_row = (const float*)d_in[3];
    const float* b_row = (const float*)d_in[4];
    float* out = (float*)d_out;

    fused_kernel<<<256, 512, 0, stream>>>(x, w_col, b_col, w_row, b_row, out);
}

// Round 12
// 52.030 us; speedup vs baseline: 1.0478x; 1.0478x over previous
//
#include <hip/hip_runtime.h>
#include <hip/hip_bf16.h>

// B=128, C=32, K=128
// out[b,c,i,j] = s[b,c],  s[b,c] = sum_k (u[c,k]+b_row[c]) * (v[c,k]+b_col[c])
//   u[c,k] = sum_i w_row[c,i] * X[b,i,k]   (xs row-slice)
//   v[c,k] = sum_j w_col[c,j] * X[b,k,j]   (xt row-slice)
//
// FUSED v4: wave-role split. R10's 8 waves all read the SAME xs+xt rows
// (8x redundant LDS x-traffic, ~3 MB/block -> compute ~10 us, LDS-BW bound).
// Now: waves 0-3 compute u (xs only), waves 4-7 compute v (xt only), 4 c's
// each via one b128 weight broadcast -> 2 b128/iter/wave, 64 iters/wave
// -> ~1 MB LDS/block. u,v meet via 16 KB exchange in the dead xs region +
// short dot pass (+2 barriers). xs unpadded (LD=128): row-slice read is a
// bank permutation, conflict-free. All-f32 (R11 bf16 staging regressed).
// Retained: non-redundant fusion (R10), XCD-paired bids, plain stores (R3).

constexpr int KDIM = 128;
constexpr int CDIM = 32;

// XOR chunk swizzle, linear [128][128] tile: conflict-free for 4x4-transpose
// b128 staging writes AND row-slice b128 reads (verified R4/R5/R10).
__device__ __forceinline__ int swz_word(int row, int col) {
    return (row << 7) | ((((col >> 2) ^ ((row >> 2) & 7)) << 2) | (col & 3));
}

// grid = 256: xcd = bid&7, idx = bid>>3; b = xcd*16 + (idx>>1), ch = idx&1
__global__ __launch_bounds__(512) void fused_kernel(
    const float* __restrict__ x,
    const float* __restrict__ w_col, const float* __restrict__ b_col,
    const float* __restrict__ w_row, const float* __restrict__ b_row,
    float* __restrict__ out)
{
    __shared__ __align__(16) float xs[KDIM * KDIM];   // X row-major (64 KB); later: u/v exchange + dead
    __shared__ __align__(16) float xt[KDIM * KDIM];   // X^T swizzled (64 KB); later: s broadcast
    __shared__ float4 wu4[KDIM][4];   // wu4[i][g] = w_row[C0+4g+0..3][i]  (8 KB)
    __shared__ float4 wc4[KDIM][4];   // wc4[j][g] = w_col[C0+4g+0..3][j]  (8 KB)

    const int bid  = blockIdx.x;
    const int xcd  = bid & 7;
    const int idx  = bid >> 3;               // 0..31
    const int b    = xcd * 16 + (idx >> 1);  // ch-pair of a b shares an XCD
    const int ch   = idx & 1;
    const int C0   = ch * 16;
    const int tid  = threadIdx.x;
    const int w    = tid >> 6;               // wave 0..7
    const int lane = tid & 63;

    // ---- stage weights: 512 threads = 128 i x 4 g, both arrays ----
    {
        const int i = tid & 127;
        const int g = tid >> 7;              // 0..3
        wu4[i][g] = make_float4(w_row[(C0 + 4 * g + 0) * KDIM + i],
                                w_row[(C0 + 4 * g + 1) * KDIM + i],
                                w_row[(C0 + 4 * g + 2) * KDIM + i],
                                w_row[(C0 + 4 * g + 3) * KDIM + i]);
        wc4[i][g] = make_float4(w_col[(C0 + 4 * g + 0) * KDIM + i],
                                w_col[(C0 + 4 * g + 1) * KDIM + i],
                                w_col[(C0 + 4 * g + 2) * KDIM + i],
                                w_col[(C0 + 4 * g + 3) * KDIM + i]);
    }

    // ---- merged X staging: 8 float4 loads/thread feed BOTH xs and xt ----
    const float4* xsrc = reinterpret_cast<const float4*>(x + (size_t)b * KDIM * KDIM);
    const int tj  = tid & 31;    // column quad of X
    const int ti0 = tid >> 5;    // 0..15
    #pragma unroll
    for (int it = 0; it < 2; ++it) {
        const int ti = ti0 + 16 * it;                     // row quad, 0..31
        const float4 r0 = xsrc[(4 * ti + 0) * 32 + tj];   // coalesced
        const float4 r1 = xsrc[(4 * ti + 1) * 32 + tj];
        const float4 r2 = xsrc[(4 * ti + 2) * 32 + tj];
        const float4 r3 = xsrc[(4 * ti + 3) * 32 + tj];
        *reinterpret_cast<float4*>(&xs[(4 * ti + 0) * KDIM + 4 * tj]) = r0;
        *reinterpret_cast<float4*>(&xs[(4 * ti + 1) * KDIM + 4 * tj]) = r1;
        *reinterpret_cast<float4*>(&xs[(4 * ti + 2) * KDIM + 4 * tj]) = r2;
        *reinterpret_cast<float4*>(&xs[(4 * ti + 3) * KDIM + 4 * tj]) = r3;
        *reinterpret_cast<float4*>(&xt[swz_word(4 * tj + 0, 4 * ti)]) =
            make_float4(r0.x, r1.x, r2.x, r3.x);
        *reinterpret_cast<float4*>(&xt[swz_word(4 * tj + 1, 4 * ti)]) =
            make_float4(r0.y, r1.y, r2.y, r3.y);
        *reinterpret_cast<float4*>(&xt[swz_word(4 * tj + 2, 4 * ti)]) =
            make_float4(r0.z, r1.z, r2.z, r3.z);
        *reinterpret_cast<float4*>(&xt[swz_word(4 * tj + 3, 4 * ti)]) =
            make_float4(r0.w, r1.w, r2.w, r3.w);
    }
    __syncthreads();   // B1

    // ---- compute: role = w>>2 (0:u from xs, 1:v from xt); g = w&3 -> c-quad ----
    const int role = w >> 2;
    const int g    = w & 3;
    const int kq   = lane & 31;    // 4-k chunk
    const int ih   = lane >> 5;    // i-half
    const int k0   = 4 * kq;

    float a[4][4] = {{0,0,0,0},{0,0,0,0},{0,0,0,0},{0,0,0,0}};   // [cc][q]

    if (role == 0) {
        #pragma unroll 8
        for (int ii = 0; ii < 64; ++ii) {
            const int i = ih * 64 + ii;
            const float4 xv = *reinterpret_cast<const float4*>(&xs[i * KDIM + k0]);
            const float4 wq = wu4[i][g];                  // broadcast
            #pragma unroll
            for (int cc = 0; cc < 4; ++cc) {
                const float ww = (&wq.x)[cc];
                a[cc][0] = fmaf(ww, xv.x, a[cc][0]);
                a[cc][1] = fmaf(ww, xv.y, a[cc][1]);
                a[cc][2] = fmaf(ww, xv.z, a[cc][2]);
                a[cc][3] = fmaf(ww, xv.w, a[cc][3]);
            }
        }
    } else {
        #pragma unroll 8
        for (int ii = 0; ii < 64; ++ii) {
            const int j = ih * 64 + ii;
            const float4 tv = *reinterpret_cast<const float4*>(&xt[swz_word(j, k0)]);
            const float4 wq = wc4[j][g];                  // broadcast
            #pragma unroll
            for (int cc = 0; cc < 4; ++cc) {
                const float ww = (&wq.x)[cc];
                a[cc][0] = fmaf(ww, tv.x, a[cc][0]);
                a[cc][1] = fmaf(ww, tv.y, a[cc][1]);
                a[cc][2] = fmaf(ww, tv.z, a[cc][2]);
                a[cc][3] = fmaf(ww, tv.w, a[cc][3]);
            }
        }
    }

    // ---- combine i-halves (xor 32) ----
    #pragma unroll
    for (int cc = 0; cc < 4; ++cc)
        #pragma unroll
        for (int q = 0; q < 4; ++q)
            a[cc][q] += __shfl_xor(a[cc][q], 32);

    __syncthreads();   // B2: all xs/xt reads done -> xs reusable as exchange

    // ---- exchange: uex = xs[0..2047], vex = xs[2048..4095] ----
    if (lane < 32) {
        float* ex = xs + role * 2048;
        #pragma unroll
        for (int cc = 0; cc < 4; ++cc) {
            *reinterpret_cast<float4*>(&ex[(4 * g + cc) * KDIM + k0]) =
                make_float4(a[cc][0], a[cc][1], a[cc][2], a[cc][3]);
        }
    }
    __syncthreads();   // B3

    // ---- dot pass: thread group cg (32 lanes) -> s[C0+cg] ----
    {
        const int cg  = tid >> 5;            // 0..15
        const int kq2 = tid & 31;
        const float4 uu = *reinterpret_cast<const float4*>(&xs[cg * KDIM + 4 * kq2]);
        const float4 vv = *reinterpret_cast<const float4*>(&xs[2048 + cg * KDIM + 4 * kq2]);
        const int c = C0 + cg;
        const float br = b_row[c];
        const float bc = b_col[c];
        float p = (uu.x + br) * (vv.x + bc) + (uu.y + br) * (vv.y + bc)
                + (uu.z + br) * (vv.z + bc) + (uu.w + br) * (vv.w + bc);
        #pragma unroll
        for (int off = 1; off < 32; off <<= 1) p += __shfl_xor(p, off, 32);
        if (kq2 == 0) xt[cg] = p;            // s broadcast slot (xt dead)
    }
    __syncthreads();   // B4

    // ---- write phase: 16 slabs (1 MB), block-wide coalesced float4 ----
    float4* out4 = reinterpret_cast<float4*>(out);
    #pragma unroll
    for (int cl = 0; cl < 16; ++cl) {
        const float val = xt[cl];            // LDS broadcast
        float4 v4;
        v4.x = v4.y = v4.z = v4.w = val;
        float4* o = out4 + (size_t)(b * CDIM + C0 + cl) * 4096;
        #pragma unroll
        for (int r = 0; r < 8; ++r) {
            o[tid + 512 * r] = v4;
        }
    }
}

extern "C" void kernel_launch(void* const* d_in, const int* in_sizes, int n_in,
                              void* d_out, int out_size, void* d_ws, size_t ws_size,
                              hipStream_t stream) {
    const float* x     = (const float*)d_in[0];
    const float* w_col = (const float*)d_in[1];
    const float* b_col = (const float*)d_in[2];
    const float* w_row = (const float*)d_in[3];
    const float* b_row = (const float*)d_in[4];
    float* out = (float*)d_out;

    fused_kernel<<<256, 512, 0, stream>>>(x, w_col, b_col, w_row, b_row, out);
}